// Round 15
// baseline (344.848 us; speedup 1.0000x reference)
//
#include <hip/hip_runtime.h>

#define T_STEPS 512
#define BATCH   64
#define HID     64
#define G3      192      // 3*HID
#define DIN     2048
#define B_BLK   16
#define NBLK    4        // BATCH / B_BLK
#define LOG2E   1.44269504088896340736f
#define LDP     196      // pbuf row stride (f32)
#define NROUND  130      // 4 GRU steps per round (R11-proven structure)

typedef float    f32x4    __attribute__((ext_vector_type(4)));
typedef short    short8   __attribute__((ext_vector_type(8)));
typedef unsigned uint32x4 __attribute__((ext_vector_type(4)));

__device__ __forceinline__ unsigned short f2bf(float f) {
    unsigned int u = __builtin_bit_cast(unsigned int, f);
    unsigned int r = u + 0x7fffu + ((u >> 16) & 1u);   // RNE
    return (unsigned short)(r >> 16);
}
__device__ __forceinline__ unsigned int cvtpk(float a, float b) {
    unsigned int r;
    asm("v_cvt_pk_bf16_f32 %0, %1, %2" : "=v"(r) : "v"(a), "v"(b));
    return r;
}
__device__ __forceinline__ float exp2neg(float x) {   // 2^(-x)
    float r; asm("v_exp_f32 %0, -%1" : "=v"(r) : "v"(x)); return r;
}
__device__ __forceinline__ float exp2pos(float x) {   // 2^(x)
    float r; asm("v_exp_f32 %0, %1" : "=v"(r) : "v"(x)); return r;
}
// barrier WITHOUT vmcnt drain: orders LDS only; global prefetch stays in flight
__device__ __forceinline__ void wg_barrier() {
    asm volatile("s_waitcnt lgkmcnt(0)" ::: "memory");
    __builtin_amdgcn_s_barrier();
    asm volatile("" ::: "memory");
}
// ---- intra-cluster (4-wave) sync: signal + single-b128 poll ----
__device__ __forceinline__ void sig_flag(volatile unsigned* f, unsigned v) {
    asm volatile("s_waitcnt lgkmcnt(0)" ::: "memory");   // h-data committed
    *f = v;
}
__device__ __forceinline__ void wait_flags(const unsigned* base, unsigned tag) {
    const unsigned addr = (unsigned)(unsigned long long)base;
    for (;;) {
        uint32x4 f;
        asm volatile("ds_read_b128 %0, %1\n\ts_waitcnt lgkmcnt(0)"
                     : "=v"(f) : "v"(addr) : "memory");
        unsigned m0 = f.x < f.y ? f.x : f.y;
        unsigned m1 = f.z < f.w ? f.z : f.w;
        if ((m0 < m1 ? m0 : m1) >= tag) break;
    }
    asm volatile("" ::: "memory");
}

// Fused GRU gate unit, exp2 domain (inputs pre-scaled by log2e / 2*log2e).
__device__ __forceinline__ float gunit(float grs, float gzs, float a2,
                                       float xn, float h) {
    float R   = 1.f + exp2neg(grs);
    float Q   = 1.f + exp2neg(gzs);
    float r   = __builtin_amdgcn_rcpf(R);
    float s   = fmaf(r, a2, xn);
    float P   = 1.f + exp2pos(s);
    float ipq = __builtin_amdgcn_rcpf(P * Q);
    float n   = fmaf(-2.f, ipq * Q, 1.f);          // tanh
    return fmaf(h - n, ipq * P, n);                // n + z*(h-n)
}

// ---------------- Kernel 1: xi = (x @ W_ih0^T + b_ih0) * gate_scale --------
#define BM  128
#define BK  64
#define LDA 72
#define LDB 72

__launch_bounds__(512, 1)
__global__ void proj0_kernel(const float* __restrict__ x,
                             const float* __restrict__ Wih0,
                             const float* __restrict__ bih0,
                             float* __restrict__ xi)
{
    __shared__ unsigned short Asm[BM * LDA];
    __shared__ unsigned short Bsm[G3 * LDB];

    const int tid  = threadIdx.x;
    const int wave = tid >> 6;
    const int lane = tid & 63;
    const int wm   = wave >> 2;
    const int wn   = wave & 3;
    const int m0   = blockIdx.x * BM;
    const int l16  = lane & 15;
    const int lk   = lane >> 4;
    const int rA   = tid >> 4;       // 0..31
    const int c4   = tid & 15;

    const float* xb = x    + (size_t)(m0 + rA) * DIN + c4 * 4;
    const float* wb = Wih0 + (size_t)rA        * DIN + c4 * 4;
    unsigned short* ap = Asm + rA * LDA + c4 * 4;
    unsigned short* bp = Bsm + rA * LDB + c4 * 4;

    f32x4 acc[4][3];
#pragma unroll
    for (int mi = 0; mi < 4; ++mi)
#pragma unroll
        for (int ni = 0; ni < 3; ++ni)
            acc[mi][ni] = (f32x4){0.f, 0.f, 0.f, 0.f};

    float4 stA[4], stB[6];
#pragma unroll
    for (int it = 0; it < 4; ++it) stA[it] = *(const float4*)(xb + it * 32 * DIN);
#pragma unroll
    for (int it = 0; it < 6; ++it) stB[it] = *(const float4*)(wb + it * 32 * DIN);

    for (int kt = 0; kt < DIN / BK; ++kt) {
#pragma unroll
        for (int it = 0; it < 4; ++it) {
            uint2 pk;
            pk.x = cvtpk(stA[it].x, stA[it].y);
            pk.y = cvtpk(stA[it].z, stA[it].w);
            *(uint2*)(ap + it * 32 * LDA) = pk;
        }
#pragma unroll
        for (int it = 0; it < 6; ++it) {
            uint2 pk;
            pk.x = cvtpk(stB[it].x, stB[it].y);
            pk.y = cvtpk(stB[it].z, stB[it].w);
            *(uint2*)(bp + it * 32 * LDB) = pk;
        }
        if (kt + 1 < DIN / BK) {
            const int kk = (kt + 1) * BK;
#pragma unroll
            for (int it = 0; it < 4; ++it) stA[it] = *(const float4*)(xb + kk + it * 32 * DIN);
#pragma unroll
            for (int it = 0; it < 6; ++it) stB[it] = *(const float4*)(wb + kk + it * 32 * DIN);
        }
        wg_barrier();

#pragma unroll
        for (int ks = 0; ks < 2; ++ks) {
            const int kb = ks * 32 + lk * 8;
            short8 a[4], bfr[3];
#pragma unroll
            for (int mi = 0; mi < 4; ++mi)
                a[mi] = *(const short8*)&Asm[(wm * 64 + mi * 16 + l16) * LDA + kb];
#pragma unroll
            for (int ni = 0; ni < 3; ++ni)
                bfr[ni] = *(const short8*)&Bsm[(wn * 48 + ni * 16 + l16) * LDB + kb];
#pragma unroll
            for (int mi = 0; mi < 4; ++mi)
#pragma unroll
                for (int ni = 0; ni < 3; ++ni)
                    acc[mi][ni] = __builtin_amdgcn_mfma_f32_16x16x32_bf16(
                        a[mi], bfr[ni], acc[mi][ni], 0, 0, 0);
        }
        wg_barrier();
    }

#pragma unroll
    for (int ni = 0; ni < 3; ++ni) {
        int g = wn * 48 + ni * 16 + l16;      // = gate*64 + row
        float sc = (g < 128) ? LOG2E : 2.f * LOG2E;
        float bias = bih0[g];
#pragma unroll
        for (int mi = 0; mi < 4; ++mi) {
#pragma unroll
            for (int r = 0; r < 4; ++r) {
                int m  = m0 + wm * 64 + mi * 16 + lk * 4 + r;
                int t  = m & 511;
                int bb = m >> 9;
                xi[(size_t)(t * BATCH + bb) * G3 + g] = (acc[mi][ni][r] + bias) * sc;
            }
        }
    }
}

// ---------------- Kernel 2: MFMA-batched fused 2-layer GRU + FC ------------
// R11-proven structure: 4 blocks x 16 batch x 12 waves (3/SIMD), FOUR GRU
// steps per WG barrier (130 rounds), intra-cluster flag sync on the serial
// h-chains only, depth-8 rings, f32 pbuf. Deltas vs R11 (both strictly safe):
//  (1) FULL ring zeroing (4096 dwords, was 2048 — slots 4-7 were garbage;
//      R11 passed only because GRU contraction forgets finite garbage).
//  (2) L0 compute at s_setprio(2) (pure scheduler hint).
//  L0 (w0-3)  @round r: h0(4r..4r+3)
//  P  (w4-7)  @round r: p(4r-4..4r-1) = Wih1@h0 + folded biases -> pbuf
//  L1 (w8-11) @round r: h1(4r-8..4r-5) = gates(p, Whh1@h1)
__launch_bounds__(768, 1)
__global__ void gru_fused_kernel(const float* __restrict__ xi,
                                 const float* __restrict__ Whh0,
                                 const float* __restrict__ bhh0,
                                 const float* __restrict__ Wih1,
                                 const float* __restrict__ bih1,
                                 const float* __restrict__ Whh1,
                                 const float* __restrict__ bhh1,
                                 const float* __restrict__ fcw,
                                 const float* __restrict__ fcb,
                                 float* __restrict__ out)
{
    __shared__ __align__(16) unsigned short h0d[8][8][B_BLK][8];   // 16 KB
    __shared__ __align__(16) unsigned short h1d[8][8][B_BLK][8];   // 16 KB
    __shared__ __align__(16) float pbuf[8][B_BLK][LDP];            // 98 KB
    __shared__ float fcbuf[B_BLK][68];
    __shared__ __align__(16) unsigned h0flag[4];
    __shared__ __align__(16) unsigned h1flag[4];

    const int tid  = threadIdx.x;
    const int w    = tid >> 6;        // wave 0..11
    const int l    = tid & 63;
    const int c    = l & 15;          // batch-in-block / MFMA col
    const int kg   = l >> 4;          // 0..3
    const int blk  = blockIdx.x;
    const int role = w >> 2;          // 0 = L0, 1 = P, 2 = L1
    const int sub  = w & 3;
    const int jw   = sub * 16;

    // ---- stationary weight fragments + bias C-inits (exp2-prescaled) ----
    short8 frag[6];
    f32x4  bC[3];
    {
        const float* Wsel = (role == 0) ? Whh0 : (role == 1) ? Wih1 : Whh1;
#pragma unroll
        for (int g = 0; g < 3; ++g) {
            const float sc = (g == 2) ? 2.f * LOG2E : LOG2E;
#pragma unroll
            for (int ks = 0; ks < 2; ++ks) {
                const size_t roff = (size_t)(g * 64 + jw + c) * HID + ks * 32 + kg * 8;
                short8 s;
#pragma unroll
                for (int j = 0; j < 8; ++j) s[j] = (short)f2bf(Wsel[roff + j] * sc);
                frag[g * 2 + ks] = s;
            }
            float4 vh0 = *(const float4*)&bhh0[g * 64 + jw + kg * 4];
            float4 vi1 = *(const float4*)&bih1[g * 64 + jw + kg * 4];
            float4 vh1 = *(const float4*)&bhh1[g * 64 + jw + kg * 4];
            if (role == 0) {
                bC[g] = (f32x4){vh0.x * sc, vh0.y * sc, vh0.z * sc, vh0.w * sc};
            } else if (role == 1) {
                if (g < 2)
                    bC[g] = (f32x4){(vi1.x + vh1.x) * sc, (vi1.y + vh1.y) * sc,
                                    (vi1.z + vh1.z) * sc, (vi1.w + vh1.w) * sc};
                else
                    bC[g] = (f32x4){vi1.x * sc, vi1.y * sc, vi1.z * sc, vi1.w * sc};
            } else {
                if (g < 2) bC[g] = (f32x4){0.f, 0.f, 0.f, 0.f};
                else       bC[g] = (f32x4){vh1.x * sc, vh1.y * sc, vh1.z * sc, vh1.w * sc};
            }
        }
    }

    float hst[4] = {0.f, 0.f, 0.f, 0.f};   // L0: h0 slice; L1: h1 slice

    // zero h rings FULLY (each 8192 ushorts = 4096 dwords) + flags
    for (int i = tid; i < 4096; i += 768) {
        ((unsigned int*)h0d)[i] = 0;
        ((unsigned int*)h1d)[i] = 0;
    }
    if (tid < 4) { h0flag[tid] = 0; h1flag[tid] = 0; }
    __syncthreads();

    const int chunk = 2 * sub + (kg >> 1);
    const int coff  = (kg & 1) * 4;

    if (role == 0) {
        // ---- L0: serial h0 chain; strongest priority outside spins ----
        __builtin_amdgcn_s_setprio(2);
        const size_t xstep = (size_t)BATCH * G3;
        const float* xp = xi + (size_t)(blk * B_BLK + c) * G3 + jw + kg * 4;
        float4 pA[3], pB[3];
        pA[0] = *(const float4*)(xp);
        pA[1] = *(const float4*)(xp + 64);
        pA[2] = *(const float4*)(xp + 128);
        pB[0] = *(const float4*)(xp + xstep);
        pB[1] = *(const float4*)(xp + xstep + 64);
        pB[2] = *(const float4*)(xp + xstep + 128);
        const float* xpr = xp + 2 * xstep;

        // s = step-in-round: s>0 -> intra-cluster flag wait for h0(t-1)
        auto stepL0 = [&](int t, int s, float4 (&cur)[3]) {
            if (s > 0) {
                __builtin_amdgcn_s_setprio(0);
                wait_flags(h0flag, (unsigned)t);
                __builtin_amdgcn_s_setprio(2);
            }
            const int pb = (t + 7) & 7;                    // (t-1)&7
            short8 x0 = *(const short8*)&h0d[pb][kg][c][0];
            short8 x1 = *(const short8*)&h0d[pb][4 + kg][c][0];
            f32x4 a0 = bC[0], a1 = bC[1], a2 = bC[2];
            a0 = __builtin_amdgcn_mfma_f32_16x16x32_bf16(frag[0], x0, a0, 0, 0, 0);
            a0 = __builtin_amdgcn_mfma_f32_16x16x32_bf16(frag[1], x1, a0, 0, 0, 0);
            a1 = __builtin_amdgcn_mfma_f32_16x16x32_bf16(frag[2], x0, a1, 0, 0, 0);
            a1 = __builtin_amdgcn_mfma_f32_16x16x32_bf16(frag[3], x1, a1, 0, 0, 0);
            a2 = __builtin_amdgcn_mfma_f32_16x16x32_bf16(frag[4], x0, a2, 0, 0, 0);
            a2 = __builtin_amdgcn_mfma_f32_16x16x32_bf16(frag[5], x1, a2, 0, 0, 0);

            float4 xr4 = cur[0], xz4 = cur[1], xn4 = cur[2];
            if (t + 2 < T_STEPS) {       // refill; rides across sync points
                cur[0] = *(const float4*)(xpr);
                cur[1] = *(const float4*)(xpr + 64);
                cur[2] = *(const float4*)(xpr + 128);
                xpr += xstep;
            }
            hst[0] = gunit(xr4.x + a0[0], xz4.x + a1[0], a2[0], xn4.x, hst[0]);
            hst[1] = gunit(xr4.y + a0[1], xz4.y + a1[1], a2[1], xn4.y, hst[1]);
            hst[2] = gunit(xr4.z + a0[2], xz4.z + a1[2], a2[2], xn4.z, hst[2]);
            hst[3] = gunit(xr4.w + a0[3], xz4.w + a1[3], a2[3], xn4.w, hst[3]);
            uint2 hw;
            hw.x = cvtpk(hst[0], hst[1]);
            hw.y = cvtpk(hst[2], hst[3]);
            *(uint2*)&h0d[t & 7][chunk][c][coff] = hw;
            if (s < 3) sig_flag(&h0flag[sub], (unsigned)(t + 1));
        };

        for (int r = 0; r < NROUND; ++r) {
            if (r < 128) {
                const int t0 = 4 * r;
                stepL0(t0 + 0, 0, pA);
                stepL0(t0 + 1, 1, pB);
                stepL0(t0 + 2, 2, pA);
                stepL0(t0 + 3, 3, pB);
            }
            wg_barrier();
        }
    } else if (role == 1) {
        // ---- P: p(k) = Wih1@h0(k) + biases (cross-cluster, barrier-paced) --
        auto stepP = [&](int k) {
            const int pb = k & 7;
            short8 x0 = *(const short8*)&h0d[pb][kg][c][0];
            short8 x1 = *(const short8*)&h0d[pb][4 + kg][c][0];
            f32x4 p0 = bC[0], p1 = bC[1], p2 = bC[2];
            p0 = __builtin_amdgcn_mfma_f32_16x16x32_bf16(frag[0], x0, p0, 0, 0, 0);
            p0 = __builtin_amdgcn_mfma_f32_16x16x32_bf16(frag[1], x1, p0, 0, 0, 0);
            p1 = __builtin_amdgcn_mfma_f32_16x16x32_bf16(frag[2], x0, p1, 0, 0, 0);
            p1 = __builtin_amdgcn_mfma_f32_16x16x32_bf16(frag[3], x1, p1, 0, 0, 0);
            p2 = __builtin_amdgcn_mfma_f32_16x16x32_bf16(frag[4], x0, p2, 0, 0, 0);
            p2 = __builtin_amdgcn_mfma_f32_16x16x32_bf16(frag[5], x1, p2, 0, 0, 0);
            float* pd = &pbuf[k & 7][c][jw + kg * 4];
            *(f32x4*)(pd)       = p0;
            *(f32x4*)(pd + 64)  = p1;
            *(f32x4*)(pd + 128) = p2;
        };
        for (int r = 0; r < NROUND; ++r) {
            if (r >= 1 && r <= 128) {
                const int k0 = 4 * r - 4;
                stepP(k0 + 0);
                stepP(k0 + 1);
                stepP(k0 + 2);
                stepP(k0 + 3);
            }
            wg_barrier();
        }
    } else {
        // ---- L1: h1(k) = gates(p(k), Whh1@h1(k-1)); serial h1 chain ----
        auto stepL1 = [&](int k, int s) {
            if (s > 0) wait_flags(h1flag, (unsigned)k);
            const int py = (k + 7) & 7;                    // (k-1)&7
            short8 y0 = *(const short8*)&h1d[py][kg][c][0];
            short8 y1 = *(const short8*)&h1d[py][4 + kg][c][0];
            f32x4 g0 = bC[0], g1 = bC[1], g2 = bC[2];
            g0 = __builtin_amdgcn_mfma_f32_16x16x32_bf16(frag[0], y0, g0, 0, 0, 0);
            g0 = __builtin_amdgcn_mfma_f32_16x16x32_bf16(frag[1], y1, g0, 0, 0, 0);
            g1 = __builtin_amdgcn_mfma_f32_16x16x32_bf16(frag[2], y0, g1, 0, 0, 0);
            g1 = __builtin_amdgcn_mfma_f32_16x16x32_bf16(frag[3], y1, g1, 0, 0, 0);
            g2 = __builtin_amdgcn_mfma_f32_16x16x32_bf16(frag[4], y0, g2, 0, 0, 0);
            g2 = __builtin_amdgcn_mfma_f32_16x16x32_bf16(frag[5], y1, g2, 0, 0, 0);

            const float* pd = &pbuf[k & 7][c][jw + kg * 4];
            f32x4 pr = *(const f32x4*)(pd);
            f32x4 pz = *(const f32x4*)(pd + 64);
            f32x4 pn = *(const f32x4*)(pd + 128);
#pragma unroll
            for (int q = 0; q < 4; ++q)
                hst[q] = gunit(pr[q] + g0[q], pz[q] + g1[q], g2[q], pn[q], hst[q]);
            uint2 hw;
            hw.x = cvtpk(hst[0], hst[1]);
            hw.y = cvtpk(hst[2], hst[3]);
            *(uint2*)&h1d[k & 7][chunk][c][coff] = hw;
            if (s < 3) sig_flag(&h1flag[sub], (unsigned)(k + 1));
        };
        for (int r = 0; r < NROUND; ++r) {
            if (r >= 2) {
                const int k0 = 4 * r - 8;
                stepL1(k0 + 0, 0);
                stepL1(k0 + 1, 1);
                stepL1(k0 + 2, 2);
                stepL1(k0 + 3, 3);
            }
            wg_barrier();
        }
    }

    // ---- FC: out[b] = h1(511) . fc_w + fc_b ----
    if (role == 2) {
#pragma unroll
        for (int q = 0; q < 4; ++q)
            fcbuf[c][jw + kg * 4 + q] = hst[q];
    }
    __syncthreads();
    if (w == 0) {
        float p = 0.f;
#pragma unroll
        for (int jj = 0; jj < 16; ++jj)
            p += fcbuf[c][kg * 16 + jj] * fcw[kg * 16 + jj];
        p += __shfl_xor(p, 16);
        p += __shfl_xor(p, 32);
        if (kg == 0) out[blk * B_BLK + c] = p + fcb[0];
    }
}

extern "C" void kernel_launch(void* const* d_in, const int* in_sizes, int n_in,
                              void* d_out, int out_size, void* d_ws, size_t ws_size,
                              hipStream_t stream)
{
    const float* x    = (const float*)d_in[0];
    const float* Wih0 = (const float*)d_in[1];
    const float* Whh0 = (const float*)d_in[2];
    const float* bih0 = (const float*)d_in[3];
    const float* bhh0 = (const float*)d_in[4];
    const float* Wih1 = (const float*)d_in[5];
    const float* Whh1 = (const float*)d_in[6];
    const float* bih1 = (const float*)d_in[7];
    const float* bhh1 = (const float*)d_in[8];
    const float* fcw  = (const float*)d_in[9];
    const float* fcb  = (const float*)d_in[10];
    float* out = (float*)d_out;
    float* xi  = (float*)d_ws;   // 512*64*192 f32 = 25.2 MB (pre-scaled)

    hipLaunchKernelGGL(proj0_kernel, dim3(32768 / BM), dim3(512), 0, stream,
                       x, Wih0, bih0, xi);
    hipLaunchKernelGGL(gru_fused_kernel, dim3(NBLK), dim3(768), 0, stream,
                       xi, Whh0, bhh0, Wih1, bih1, Whh1, bhh1, fcw, fcb, out);
}

// Round 16
// 341.602 us; speedup vs baseline: 1.0095x; 1.0095x over previous
//
#include <hip/hip_runtime.h>

#define T_STEPS 512
#define BATCH   64
#define HID     64
#define G3      192      // 3*HID
#define DIN     2048
#define B_BLK   16
#define NBLK    4        // BATCH / B_BLK
#define LOG2E   1.44269504088896340736f
#define LDP     196      // pbuf row stride (f32)
#define NROUND  130      // 4 GRU steps per round (R11/R15-proven structure)

typedef float    f32x4    __attribute__((ext_vector_type(4)));
typedef short    short8   __attribute__((ext_vector_type(8)));
typedef unsigned uint32x4 __attribute__((ext_vector_type(4)));

__device__ __forceinline__ unsigned short f2bf(float f) {
    unsigned int u = __builtin_bit_cast(unsigned int, f);
    unsigned int r = u + 0x7fffu + ((u >> 16) & 1u);   // RNE
    return (unsigned short)(r >> 16);
}
__device__ __forceinline__ unsigned int cvtpk(float a, float b) {
    unsigned int r;
    asm("v_cvt_pk_bf16_f32 %0, %1, %2" : "=v"(r) : "v"(a), "v"(b));
    return r;
}
__device__ __forceinline__ float exp2neg(float x) {   // 2^(-x)
    float r; asm("v_exp_f32 %0, -%1" : "=v"(r) : "v"(x)); return r;
}
__device__ __forceinline__ float exp2pos(float x) {   // 2^(x)
    float r; asm("v_exp_f32 %0, %1" : "=v"(r) : "v"(x)); return r;
}
// barrier WITHOUT vmcnt drain: orders LDS only; global prefetch stays in flight
__device__ __forceinline__ void wg_barrier() {
    asm volatile("s_waitcnt lgkmcnt(0)" ::: "memory");
    __builtin_amdgcn_s_barrier();
    asm volatile("" ::: "memory");
}
// ---- intra-cluster (4-wave) sync: signal + single-b128 poll ----
__device__ __forceinline__ void sig_flag(volatile unsigned* f, unsigned v) {
    asm volatile("s_waitcnt lgkmcnt(0)" ::: "memory");   // h-data committed
    *f = v;
}
__device__ __forceinline__ void wait_flags(const unsigned* base, unsigned tag) {
    const unsigned addr = (unsigned)(unsigned long long)base;
    for (;;) {
        uint32x4 f;
        asm volatile("ds_read_b128 %0, %1\n\ts_waitcnt lgkmcnt(0)"
                     : "=v"(f) : "v"(addr) : "memory");
        unsigned m0 = f.x < f.y ? f.x : f.y;
        unsigned m1 = f.z < f.w ? f.z : f.w;
        if ((m0 < m1 ? m0 : m1) >= tag) break;
    }
    asm volatile("" ::: "memory");
}

// Fused GRU gate unit, exp2 domain (inputs pre-scaled by log2e / 2*log2e).
__device__ __forceinline__ float gunit(float grs, float gzs, float a2,
                                       float xn, float h) {
    float R   = 1.f + exp2neg(grs);
    float Q   = 1.f + exp2neg(gzs);
    float r   = __builtin_amdgcn_rcpf(R);
    float s   = fmaf(r, a2, xn);
    float P   = 1.f + exp2pos(s);
    float ipq = __builtin_amdgcn_rcpf(P * Q);
    float n   = fmaf(-2.f, ipq * Q, 1.f);          // tanh
    return fmaf(h - n, ipq * P, n);                // n + z*(h-n)
}

// ---------------- Kernel 1: xi = (x @ W_ih0^T + b_ih0) * gate_scale --------
// Depth-2 register staging: loads for k-tile kt+2 issued while packing kt,
// so each stage has two full tile-times (~3600 cyc) of HBM latency cover.
// Two NAMED stage-reg sets (rule #20: no runtime-indexed arrays).
#define BM  128
#define BK  64
#define LDA 72
#define LDB 72

__launch_bounds__(512, 1)
__global__ void proj0_kernel(const float* __restrict__ x,
                             const float* __restrict__ Wih0,
                             const float* __restrict__ bih0,
                             float* __restrict__ xi)
{
    __shared__ unsigned short Asm[BM * LDA];
    __shared__ unsigned short Bsm[G3 * LDB];

    const int tid  = threadIdx.x;
    const int wave = tid >> 6;
    const int lane = tid & 63;
    const int wm   = wave >> 2;
    const int wn   = wave & 3;
    const int m0   = blockIdx.x * BM;
    const int l16  = lane & 15;
    const int lk   = lane >> 4;
    const int rA   = tid >> 4;       // 0..31
    const int c4   = tid & 15;

    const float* xb = x    + (size_t)(m0 + rA) * DIN + c4 * 4;
    const float* wb = Wih0 + (size_t)rA        * DIN + c4 * 4;
    unsigned short* ap = Asm + rA * LDA + c4 * 4;
    unsigned short* bp = Bsm + rA * LDB + c4 * 4;

    f32x4 acc[4][3];
#pragma unroll
    for (int mi = 0; mi < 4; ++mi)
#pragma unroll
        for (int ni = 0; ni < 3; ++ni)
            acc[mi][ni] = (f32x4){0.f, 0.f, 0.f, 0.f};

    float4 sA0[4], sB0[6], sA1[4], sB1[6];
    // prologue: stages for kt = 0 and kt = 1
#pragma unroll
    for (int it = 0; it < 4; ++it) sA0[it] = *(const float4*)(xb + it * 32 * DIN);
#pragma unroll
    for (int it = 0; it < 6; ++it) sB0[it] = *(const float4*)(wb + it * 32 * DIN);
#pragma unroll
    for (int it = 0; it < 4; ++it) sA1[it] = *(const float4*)(xb + BK + it * 32 * DIN);
#pragma unroll
    for (int it = 0; it < 6; ++it) sB1[it] = *(const float4*)(wb + BK + it * 32 * DIN);

    auto tile = [&](int kt, float4 (&sA)[4], float4 (&sB)[6]) {
        // pack this stage's regs -> LDS (compiler waits only this stage's vmcnt)
#pragma unroll
        for (int it = 0; it < 4; ++it) {
            uint2 pk;
            pk.x = cvtpk(sA[it].x, sA[it].y);
            pk.y = cvtpk(sA[it].z, sA[it].w);
            *(uint2*)(ap + it * 32 * LDA) = pk;
        }
#pragma unroll
        for (int it = 0; it < 6; ++it) {
            uint2 pk;
            pk.x = cvtpk(sB[it].x, sB[it].y);
            pk.y = cvtpk(sB[it].z, sB[it].w);
            *(uint2*)(bp + it * 32 * LDB) = pk;
        }
        // refill same regs with k-tile kt+2; rides across both barriers + MFMA
        if (kt + 2 < DIN / BK) {
            const int kk = (kt + 2) * BK;
#pragma unroll
            for (int it = 0; it < 4; ++it) sA[it] = *(const float4*)(xb + kk + it * 32 * DIN);
#pragma unroll
            for (int it = 0; it < 6; ++it) sB[it] = *(const float4*)(wb + kk + it * 32 * DIN);
        }
        wg_barrier();

#pragma unroll
        for (int ks = 0; ks < 2; ++ks) {
            const int kb = ks * 32 + lk * 8;
            short8 a[4], bfr[3];
#pragma unroll
            for (int mi = 0; mi < 4; ++mi)
                a[mi] = *(const short8*)&Asm[(wm * 64 + mi * 16 + l16) * LDA + kb];
#pragma unroll
            for (int ni = 0; ni < 3; ++ni)
                bfr[ni] = *(const short8*)&Bsm[(wn * 48 + ni * 16 + l16) * LDB + kb];
#pragma unroll
            for (int mi = 0; mi < 4; ++mi)
#pragma unroll
                for (int ni = 0; ni < 3; ++ni)
                    acc[mi][ni] = __builtin_amdgcn_mfma_f32_16x16x32_bf16(
                        a[mi], bfr[ni], acc[mi][ni], 0, 0, 0);
        }
        wg_barrier();
    };

    for (int kt2 = 0; kt2 < DIN / BK; kt2 += 2) {
        tile(kt2, sA0, sB0);
        tile(kt2 + 1, sA1, sB1);
    }

#pragma unroll
    for (int ni = 0; ni < 3; ++ni) {
        int g = wn * 48 + ni * 16 + l16;      // = gate*64 + row
        float sc = (g < 128) ? LOG2E : 2.f * LOG2E;
        float bias = bih0[g];
#pragma unroll
        for (int mi = 0; mi < 4; ++mi) {
#pragma unroll
            for (int r = 0; r < 4; ++r) {
                int m  = m0 + wm * 64 + mi * 16 + lk * 4 + r;
                int t  = m & 511;
                int bb = m >> 9;
                xi[(size_t)(t * BATCH + bb) * G3 + g] = (acc[mi][ni][r] + bias) * sc;
            }
        }
    }
}

// ---------------- Kernel 2: MFMA-batched fused 2-layer GRU + FC ------------
// BYTE-IDENTICAL to R15 (passing, 277 µs): 4 blocks x 16 batch x 12 waves
// (3/SIMD), FOUR GRU steps per WG barrier (130 rounds), intra-cluster flag
// sync on serial h-chains only, depth-8 rings, f32 pbuf, full ring zeroing.
//  L0 (w0-3)  @round r: h0(4r..4r+3)
//  P  (w4-7)  @round r: p(4r-4..4r-1) = Wih1@h0 + folded biases -> pbuf
//  L1 (w8-11) @round r: h1(4r-8..4r-5) = gates(p, Whh1@h1)
__launch_bounds__(768, 1)
__global__ void gru_fused_kernel(const float* __restrict__ xi,
                                 const float* __restrict__ Whh0,
                                 const float* __restrict__ bhh0,
                                 const float* __restrict__ Wih1,
                                 const float* __restrict__ bih1,
                                 const float* __restrict__ Whh1,
                                 const float* __restrict__ bhh1,
                                 const float* __restrict__ fcw,
                                 const float* __restrict__ fcb,
                                 float* __restrict__ out)
{
    __shared__ __align__(16) unsigned short h0d[8][8][B_BLK][8];   // 16 KB
    __shared__ __align__(16) unsigned short h1d[8][8][B_BLK][8];   // 16 KB
    __shared__ __align__(16) float pbuf[8][B_BLK][LDP];            // 98 KB
    __shared__ float fcbuf[B_BLK][68];
    __shared__ __align__(16) unsigned h0flag[4];
    __shared__ __align__(16) unsigned h1flag[4];

    const int tid  = threadIdx.x;
    const int w    = tid >> 6;        // wave 0..11
    const int l    = tid & 63;
    const int c    = l & 15;          // batch-in-block / MFMA col
    const int kg   = l >> 4;          // 0..3
    const int blk  = blockIdx.x;
    const int role = w >> 2;          // 0 = L0, 1 = P, 2 = L1
    const int sub  = w & 3;
    const int jw   = sub * 16;

    // ---- stationary weight fragments + bias C-inits (exp2-prescaled) ----
    short8 frag[6];
    f32x4  bC[3];
    {
        const float* Wsel = (role == 0) ? Whh0 : (role == 1) ? Wih1 : Whh1;
#pragma unroll
        for (int g = 0; g < 3; ++g) {
            const float sc = (g == 2) ? 2.f * LOG2E : LOG2E;
#pragma unroll
            for (int ks = 0; ks < 2; ++ks) {
                const size_t roff = (size_t)(g * 64 + jw + c) * HID + ks * 32 + kg * 8;
                short8 s;
#pragma unroll
                for (int j = 0; j < 8; ++j) s[j] = (short)f2bf(Wsel[roff + j] * sc);
                frag[g * 2 + ks] = s;
            }
            float4 vh0 = *(const float4*)&bhh0[g * 64 + jw + kg * 4];
            float4 vi1 = *(const float4*)&bih1[g * 64 + jw + kg * 4];
            float4 vh1 = *(const float4*)&bhh1[g * 64 + jw + kg * 4];
            if (role == 0) {
                bC[g] = (f32x4){vh0.x * sc, vh0.y * sc, vh0.z * sc, vh0.w * sc};
            } else if (role == 1) {
                if (g < 2)
                    bC[g] = (f32x4){(vi1.x + vh1.x) * sc, (vi1.y + vh1.y) * sc,
                                    (vi1.z + vh1.z) * sc, (vi1.w + vh1.w) * sc};
                else
                    bC[g] = (f32x4){vi1.x * sc, vi1.y * sc, vi1.z * sc, vi1.w * sc};
            } else {
                if (g < 2) bC[g] = (f32x4){0.f, 0.f, 0.f, 0.f};
                else       bC[g] = (f32x4){vh1.x * sc, vh1.y * sc, vh1.z * sc, vh1.w * sc};
            }
        }
    }

    float hst[4] = {0.f, 0.f, 0.f, 0.f};   // L0: h0 slice; L1: h1 slice

    // zero h rings FULLY (each 8192 ushorts = 4096 dwords) + flags
    for (int i = tid; i < 4096; i += 768) {
        ((unsigned int*)h0d)[i] = 0;
        ((unsigned int*)h1d)[i] = 0;
    }
    if (tid < 4) { h0flag[tid] = 0; h1flag[tid] = 0; }
    __syncthreads();

    const int chunk = 2 * sub + (kg >> 1);
    const int coff  = (kg & 1) * 4;

    if (role == 0) {
        // ---- L0: serial h0 chain; strongest priority outside spins ----
        __builtin_amdgcn_s_setprio(2);
        const size_t xstep = (size_t)BATCH * G3;
        const float* xp = xi + (size_t)(blk * B_BLK + c) * G3 + jw + kg * 4;
        float4 pA[3], pB[3];
        pA[0] = *(const float4*)(xp);
        pA[1] = *(const float4*)(xp + 64);
        pA[2] = *(const float4*)(xp + 128);
        pB[0] = *(const float4*)(xp + xstep);
        pB[1] = *(const float4*)(xp + xstep + 64);
        pB[2] = *(const float4*)(xp + xstep + 128);
        const float* xpr = xp + 2 * xstep;

        // s = step-in-round: s>0 -> intra-cluster flag wait for h0(t-1)
        auto stepL0 = [&](int t, int s, float4 (&cur)[3]) {
            if (s > 0) {
                __builtin_amdgcn_s_setprio(0);
                wait_flags(h0flag, (unsigned)t);
                __builtin_amdgcn_s_setprio(2);
            }
            const int pb = (t + 7) & 7;                    // (t-1)&7
            short8 x0 = *(const short8*)&h0d[pb][kg][c][0];
            short8 x1 = *(const short8*)&h0d[pb][4 + kg][c][0];
            f32x4 a0 = bC[0], a1 = bC[1], a2 = bC[2];
            a0 = __builtin_amdgcn_mfma_f32_16x16x32_bf16(frag[0], x0, a0, 0, 0, 0);
            a0 = __builtin_amdgcn_mfma_f32_16x16x32_bf16(frag[1], x1, a0, 0, 0, 0);
            a1 = __builtin_amdgcn_mfma_f32_16x16x32_bf16(frag[2], x0, a1, 0, 0, 0);
            a1 = __builtin_amdgcn_mfma_f32_16x16x32_bf16(frag[3], x1, a1, 0, 0, 0);
            a2 = __builtin_amdgcn_mfma_f32_16x16x32_bf16(frag[4], x0, a2, 0, 0, 0);
            a2 = __builtin_amdgcn_mfma_f32_16x16x32_bf16(frag[5], x1, a2, 0, 0, 0);

            float4 xr4 = cur[0], xz4 = cur[1], xn4 = cur[2];
            if (t + 2 < T_STEPS) {       // refill; rides across sync points
                cur[0] = *(const float4*)(xpr);
                cur[1] = *(const float4*)(xpr + 64);
                cur[2] = *(const float4*)(xpr + 128);
                xpr += xstep;
            }
            hst[0] = gunit(xr4.x + a0[0], xz4.x + a1[0], a2[0], xn4.x, hst[0]);
            hst[1] = gunit(xr4.y + a0[1], xz4.y + a1[1], a2[1], xn4.y, hst[1]);
            hst[2] = gunit(xr4.z + a0[2], xz4.z + a1[2], a2[2], xn4.z, hst[2]);
            hst[3] = gunit(xr4.w + a0[3], xz4.w + a1[3], a2[3], xn4.w, hst[3]);
            uint2 hw;
            hw.x = cvtpk(hst[0], hst[1]);
            hw.y = cvtpk(hst[2], hst[3]);
            *(uint2*)&h0d[t & 7][chunk][c][coff] = hw;
            if (s < 3) sig_flag(&h0flag[sub], (unsigned)(t + 1));
        };

        for (int r = 0; r < NROUND; ++r) {
            if (r < 128) {
                const int t0 = 4 * r;
                stepL0(t0 + 0, 0, pA);
                stepL0(t0 + 1, 1, pB);
                stepL0(t0 + 2, 2, pA);
                stepL0(t0 + 3, 3, pB);
            }
            wg_barrier();
        }
    } else if (role == 1) {
        // ---- P: p(k) = Wih1@h0(k) + biases (cross-cluster, barrier-paced) --
        auto stepP = [&](int k) {
            const int pb = k & 7;
            short8 x0 = *(const short8*)&h0d[pb][kg][c][0];
            short8 x1 = *(const short8*)&h0d[pb][4 + kg][c][0];
            f32x4 p0 = bC[0], p1 = bC[1], p2 = bC[2];
            p0 = __builtin_amdgcn_mfma_f32_16x16x32_bf16(frag[0], x0, p0, 0, 0, 0);
            p0 = __builtin_amdgcn_mfma_f32_16x16x32_bf16(frag[1], x1, p0, 0, 0, 0);
            p1 = __builtin_amdgcn_mfma_f32_16x16x32_bf16(frag[2], x0, p1, 0, 0, 0);
            p1 = __builtin_amdgcn_mfma_f32_16x16x32_bf16(frag[3], x1, p1, 0, 0, 0);
            p2 = __builtin_amdgcn_mfma_f32_16x16x32_bf16(frag[4], x0, p2, 0, 0, 0);
            p2 = __builtin_amdgcn_mfma_f32_16x16x32_bf16(frag[5], x1, p2, 0, 0, 0);
            float* pd = &pbuf[k & 7][c][jw + kg * 4];
            *(f32x4*)(pd)       = p0;
            *(f32x4*)(pd + 64)  = p1;
            *(f32x4*)(pd + 128) = p2;
        };
        for (int r = 0; r < NROUND; ++r) {
            if (r >= 1 && r <= 128) {
                const int k0 = 4 * r - 4;
                stepP(k0 + 0);
                stepP(k0 + 1);
                stepP(k0 + 2);
                stepP(k0 + 3);
            }
            wg_barrier();
        }
    } else {
        // ---- L1: h1(k) = gates(p(k), Whh1@h1(k-1)); serial h1 chain ----
        auto stepL1 = [&](int k, int s) {
            if (s > 0) wait_flags(h1flag, (unsigned)k);
            const int py = (k + 7) & 7;                    // (k-1)&7
            short8 y0 = *(const short8*)&h1d[py][kg][c][0];
            short8 y1 = *(const short8*)&h1d[py][4 + kg][c][0];
            f32x4 g0 = bC[0], g1 = bC[1], g2 = bC[2];
            g0 = __builtin_amdgcn_mfma_f32_16x16x32_bf16(frag[0], y0, g0, 0, 0, 0);
            g0 = __builtin_amdgcn_mfma_f32_16x16x32_bf16(frag[1], y1, g0, 0, 0, 0);
            g1 = __builtin_amdgcn_mfma_f32_16x16x32_bf16(frag[2], y0, g1, 0, 0, 0);
            g1 = __builtin_amdgcn_mfma_f32_16x16x32_bf16(frag[3], y1, g1, 0, 0, 0);
            g2 = __builtin_amdgcn_mfma_f32_16x16x32_bf16(frag[4], y0, g2, 0, 0, 0);
            g2 = __builtin_amdgcn_mfma_f32_16x16x32_bf16(frag[5], y1, g2, 0, 0, 0);

            const float* pd = &pbuf[k & 7][c][jw + kg * 4];
            f32x4 pr = *(const f32x4*)(pd);
            f32x4 pz = *(const f32x4*)(pd + 64);
            f32x4 pn = *(const f32x4*)(pd + 128);
#pragma unroll
            for (int q = 0; q < 4; ++q)
                hst[q] = gunit(pr[q] + g0[q], pz[q] + g1[q], g2[q], pn[q], hst[q]);
            uint2 hw;
            hw.x = cvtpk(hst[0], hst[1]);
            hw.y = cvtpk(hst[2], hst[3]);
            *(uint2*)&h1d[k & 7][chunk][c][coff] = hw;
            if (s < 3) sig_flag(&h1flag[sub], (unsigned)(k + 1));
        };
        for (int r = 0; r < NROUND; ++r) {
            if (r >= 2) {
                const int k0 = 4 * r - 8;
                stepL1(k0 + 0, 0);
                stepL1(k0 + 1, 1);
                stepL1(k0 + 2, 2);
                stepL1(k0 + 3, 3);
            }
            wg_barrier();
        }
    }

    // ---- FC: out[b] = h1(511) . fc_w + fc_b ----
    if (role == 2) {
#pragma unroll
        for (int q = 0; q < 4; ++q)
            fcbuf[c][jw + kg * 4 + q] = hst[q];
    }
    __syncthreads();
    if (w == 0) {
        float p = 0.f;
#pragma unroll
        for (int jj = 0; jj < 16; ++jj)
            p += fcbuf[c][kg * 16 + jj] * fcw[kg * 16 + jj];
        p += __shfl_xor(p, 16);
        p += __shfl_xor(p, 32);
        if (kg == 0) out[blk * B_BLK + c] = p + fcb[0];
    }
}

extern "C" void kernel_launch(void* const* d_in, const int* in_sizes, int n_in,
                              void* d_out, int out_size, void* d_ws, size_t ws_size,
                              hipStream_t stream)
{
    const float* x    = (const float*)d_in[0];
    const float* Wih0 = (const float*)d_in[1];
    const float* Whh0 = (const float*)d_in[2];
    const float* bih0 = (const float*)d_in[3];
    const float* bhh0 = (const float*)d_in[4];
    const float* Wih1 = (const float*)d_in[5];
    const float* Whh1 = (const float*)d_in[6];
    const float* bih1 = (const float*)d_in[7];
    const float* bhh1 = (const float*)d_in[8];
    const float* fcw  = (const float*)d_in[9];
    const float* fcb  = (const float*)d_in[10];
    float* out = (float*)d_out;
    float* xi  = (float*)d_ws;   // 512*64*192 f32 = 25.2 MB (pre-scaled)

    hipLaunchKernelGGL(proj0_kernel, dim3(32768 / BM), dim3(512), 0, stream,
                       x, Wih0, bih0, xi);
    hipLaunchKernelGGL(gru_fused_kernel, dim3(NBLK), dim3(768), 0, stream,
                       xi, Whh0, bhh0, Wih1, bih1, Whh1, bhh1, fcw, fcb, out);
}